// Round 1
// baseline (13312.894 us; speedup 1.0000x reference)
//
#include <hip/hip_runtime.h>
#include <hip/hip_bf16.h>

// Problem constants (fixed by the reference)
#define NN 50000
#define TT 16
#define FIN 16
#define GH 64     // GCN_H == GRU_H == 64
#define EH 128    // EDGE_H
#define EE 800000

// ---------------- ws layout (bytes) ----------------
// dinv  : N f32      @ 0
// snorm : N f32      @ 200704
// flow  : N f32      @ 401408
// wc    : 192*16 f32 @ 602112   (packed [f4][192] float4)
// bc    : 192 f32    @ 614400
// wb    : 192 f32    @ 615168
// emb   : N*64 f32   @ 616192
// agg   : N*T*16 f32 @ 13416192  (layout [n][t][16])
// total ~64.6 MB
#define WS_DINV  0
#define WS_SNORM 200704
#define WS_FLOW  401408
#define WS_WC    602112
#define WS_BC    614400
#define WS_WB    615168
#define WS_EMB   616192
#define WS_AGG   13416192

__global__ __launch_bounds__(256) void k_init(float* deg, float* flow) {
    int n = blockIdx.x * 256 + threadIdx.x;
    if (n < NN) { deg[n] = 1.0f; flow[n] = 0.0f; }
}

__global__ __launch_bounds__(256) void k_deg(const int* __restrict__ ei, float* deg) {
    int e = blockIdx.x * 256 + threadIdx.x;
    if (e < EE) atomicAdd(&deg[ei[EE + e]], 1.0f);
}

__global__ __launch_bounds__(256) void k_dinv(float* deg_dinv, float* snorm) {
    int n = blockIdx.x * 256 + threadIdx.x;
    if (n < NN) {
        float d = rsqrtf(deg_dinv[n]);
        deg_dinv[n] = d;
        snorm[n] = d * d;   // self-loop norm contribution
    }
}

// Wc = W_ih @ gcn_W  (192x16, packed [f4][192] float4), wb = W_ih @ gcn_b, bc = b_ih
__global__ __launch_bounds__(256) void k_prep(const float* __restrict__ Wih,
                                              const float* __restrict__ bih,
                                              const float* __restrict__ gcnW,
                                              const float* __restrict__ gcnb,
                                              float* wc, float* bc, float* wb) {
    int tid = blockIdx.x * 256 + threadIdx.x;
    if (tid < 3072) {
        int f = tid & 15, row = tid >> 4;
        float s = 0.f;
        for (int k = 0; k < 64; k++) s += Wih[row * 64 + k] * gcnW[k * 16 + f];
        wc[((f >> 2) * 192 + row) * 4 + (f & 3)] = s;
    } else if (tid < 3264) {
        int row = tid - 3072;
        float s = 0.f;
        for (int k = 0; k < 64; k++) s += Wih[row * 64 + k] * gcnb[k];
        wb[row] = s;
        bc[row] = bih[row];
    }
}

// agg[n][t][0:16] = dinv[n]^2 * x[t][n][0:16]   (self-loop term, also initializes agg)
__global__ __launch_bounds__(256) void k_selfagg(const float* __restrict__ x,
                                                 const float* __restrict__ dinv,
                                                 float* __restrict__ agg) {
    int tid = blockIdx.x * 256 + threadIdx.x;   // over N*T
    if (tid >= NN * TT) return;
    int n = tid >> 4, t = tid & 15;
    float d = dinv[n];
    float d2 = d * d;
    const float4* xs = (const float4*)(x + ((size_t)t * NN + n) * 16);
    float4* ag = (float4*)(agg + ((size_t)n * 16 + t) * 16);
    for (int q = 0; q < 4; q++) {
        float4 v = xs[q];
        ag[q] = make_float4(d2 * v.x, d2 * v.y, d2 * v.z, d2 * v.w);
    }
}

// For each (t, edge): agg[col][t] += norm_e * x[t][row];  snorm[col] += norm_e (t==0 only)
__global__ __launch_bounds__(256) void k_scatter(const float* __restrict__ x,
                                                 const int* __restrict__ ei,
                                                 const float* __restrict__ dinv,
                                                 float* __restrict__ agg,
                                                 float* __restrict__ snorm) {
    int e = blockIdx.x * 256 + threadIdx.x;
    if (e >= EE) return;
    int t = blockIdx.y;
    int r = ei[e], c = ei[EE + e];
    float nrm = dinv[r] * dinv[c];
    if (t == 0) atomicAdd(&snorm[c], nrm);
    const float4* xs = (const float4*)(x + ((size_t)t * NN + r) * 16);
    float* ag = agg + ((size_t)c * 16 + t) * 16;
    for (int q = 0; q < 4; q++) {
        float4 v = xs[q];
        atomicAdd(ag + q * 4 + 0, nrm * v.x);
        atomicAdd(ag + q * 4 + 1, nrm * v.y);
        atomicAdd(ag + q * 4 + 2, nrm * v.z);
        atomicAdd(ag + q * 4 + 3, nrm * v.w);
    }
}

// Fused GCN-transform + GRU over T. 4 waves/block, NB nodes per wave.
#define NB 8
__global__ __launch_bounds__(256) void k_gru(const float* __restrict__ agg,
                                             const float* __restrict__ snorm,
                                             const float* __restrict__ wcP,
                                             const float* __restrict__ bc,
                                             const float* __restrict__ wb,
                                             const float* __restrict__ whh,
                                             const float* __restrict__ bhh,
                                             float* __restrict__ emb) {
    __shared__ float4 sWhh[16][192];       // [k4][row] = W_hh[row][4k4..4k4+3]
    __shared__ float4 sHs[4][NB][16];      // per-wave hidden state, float4 over k
    int tid = threadIdx.x;
    for (int i = tid; i < 3072; i += 256) {
        int k4 = i / 192, row = i % 192;
        const float* p = whh + row * 64 + k4 * 4;
        sWhh[k4][row] = make_float4(p[0], p[1], p[2], p[3]);
    }
    int w = tid >> 6, j = tid & 63;
    float4 wcR[3][4];
    float bcR[3], wbR[3], bhhR[3];
    for (int g = 0; g < 3; g++) {
        for (int f4 = 0; f4 < 4; f4++)
            wcR[g][f4] = ((const float4*)wcP)[f4 * 192 + g * 64 + j];
        bcR[g]  = bc[g * 64 + j];
        wbR[g]  = wb[g * 64 + j];
        bhhR[g] = bhh[g * 64 + j];
    }
    int base = blockIdx.x * (4 * NB) + w * NB;
    float hsreg[NB];
    float snr[NB];
    int nidx[NB];
    for (int m = 0; m < NB; m++) {
        int n = base + m;
        nidx[m] = (n < NN) ? n : (NN - 1);
        snr[m] = snorm[nidx[m]];
        hsreg[m] = 0.f;
        ((float*)&sHs[w][m][0])[j] = 0.f;
    }
    __syncthreads();

    for (int t = 0; t < TT; t++) {
        float gi[NB][3], gh[NB][3];
        for (int m = 0; m < NB; m++) {
            const float4* a4 = (const float4*)(agg + ((size_t)nidx[m] * 16 + t) * 16);
            gi[m][0] = bcR[0] + snr[m] * wbR[0];
            gi[m][1] = bcR[1] + snr[m] * wbR[1];
            gi[m][2] = bcR[2] + snr[m] * wbR[2];
            for (int f4 = 0; f4 < 4; f4++) {
                float4 av = a4[f4];
                for (int g = 0; g < 3; g++) {
                    gi[m][g] += wcR[g][f4].x * av.x + wcR[g][f4].y * av.y
                              + wcR[g][f4].z * av.z + wcR[g][f4].w * av.w;
                }
            }
            gh[m][0] = bhhR[0]; gh[m][1] = bhhR[1]; gh[m][2] = bhhR[2];
        }
        for (int k4 = 0; k4 < 16; k4++) {
            float4 w0 = sWhh[k4][j];
            float4 w1 = sWhh[k4][64 + j];
            float4 w2 = sWhh[k4][128 + j];
            for (int m = 0; m < NB; m++) {
                float4 h4 = sHs[w][m][k4];
                gh[m][0] += w0.x * h4.x + w0.y * h4.y + w0.z * h4.z + w0.w * h4.w;
                gh[m][1] += w1.x * h4.x + w1.y * h4.y + w1.z * h4.z + w1.w * h4.w;
                gh[m][2] += w2.x * h4.x + w2.y * h4.y + w2.z * h4.z + w2.w * h4.w;
            }
        }
        __syncthreads();
        for (int m = 0; m < NB; m++) {
            float r = 1.f / (1.f + __expf(-(gi[m][0] + gh[m][0])));
            float z = 1.f / (1.f + __expf(-(gi[m][1] + gh[m][1])));
            float a = gi[m][2] + r * gh[m][2];
            a = fminf(fmaxf(a, -15.f), 15.f);
            float e2 = __expf(2.f * a);
            float nn = (e2 - 1.f) / (e2 + 1.f);
            hsreg[m] = (1.f - z) * nn + z * hsreg[m];
            ((float*)&sHs[w][m][0])[j] = hsreg[m];
        }
        __syncthreads();
    }
    for (int m = 0; m < NB; m++) {
        int n = base + m;
        if (n < NN) emb[(size_t)n * 64 + j] = hsreg[m];
    }
}

// Edge MLP: per wave 16 edges; lane = eg(4 groups of 4 edges) x hg(16 groups of 8 hidden)
__global__ __launch_bounds__(256) void k_edge(const float* __restrict__ emb,
                                              const float* __restrict__ ea,
                                              const int* __restrict__ ei,
                                              const float* __restrict__ e1W,
                                              const float* __restrict__ e1b,
                                              const float* __restrict__ e2W,
                                              const float* __restrict__ e2b,
                                              float* __restrict__ pred_edge,
                                              float* __restrict__ flow) {
    __shared__ float4 sIn[4][16 * 33];   // per wave: 16 edges x 33 float4 (132 f32)
    int tid = threadIdx.x;
    int w = tid >> 6, l = tid & 63;
    int e0 = (blockIdx.x * 4 + w) * 16;
    for (int i = l; i < 528; i += 64) {
        int ed = i / 33, comp = i - ed * 33;
        int e = e0 + ed;
        float4 v;
        if (comp < 16) {
            int r = ei[e];
            v = ((const float4*)(emb + (size_t)r * 64))[comp];
        } else if (comp < 32) {
            int c = ei[EE + e];
            v = ((const float4*)(emb + (size_t)c * 64))[comp - 16];
        } else {
            v = ((const float4*)ea)[e];
        }
        sIn[w][ed * 33 + comp] = v;
    }
    __syncthreads();
    int hg = l & 15, eg = l >> 4;
    float acc[4][8];
    for (int q = 0; q < 4; q++)
        for (int hh = 0; hh < 8; hh++) acc[q][hh] = 0.f;
    const float* wbase = e1W + (size_t)(hg * 8) * 132;
    for (int k4 = 0; k4 < 33; k4++) {
        float4 wv[8];
        for (int hh = 0; hh < 8; hh++)
            wv[hh] = *(const float4*)(wbase + hh * 132 + k4 * 4);
        for (int q = 0; q < 4; q++) {
            float4 iv = sIn[w][(eg * 4 + q) * 33 + k4];
            for (int hh = 0; hh < 8; hh++)
                acc[q][hh] += wv[hh].x * iv.x + wv[hh].y * iv.y
                            + wv[hh].z * iv.z + wv[hh].w * iv.w;
        }
    }
    float4 b1a = ((const float4*)e1b)[hg * 2], b1b = ((const float4*)e1b)[hg * 2 + 1];
    float4 w2a = ((const float4*)e2W)[hg * 2], w2b = ((const float4*)e2W)[hg * 2 + 1];
    float part[4];
    for (int q = 0; q < 4; q++) {
        float s = 0.f;
        s += w2a.x * fmaxf(acc[q][0] + b1a.x, 0.f);
        s += w2a.y * fmaxf(acc[q][1] + b1a.y, 0.f);
        s += w2a.z * fmaxf(acc[q][2] + b1a.z, 0.f);
        s += w2a.w * fmaxf(acc[q][3] + b1a.w, 0.f);
        s += w2b.x * fmaxf(acc[q][4] + b1b.x, 0.f);
        s += w2b.y * fmaxf(acc[q][5] + b1b.y, 0.f);
        s += w2b.z * fmaxf(acc[q][6] + b1b.z, 0.f);
        s += w2b.w * fmaxf(acc[q][7] + b1b.w, 0.f);
        part[q] = s;
    }
    for (int m = 1; m < 16; m <<= 1)
        for (int q = 0; q < 4; q++) part[q] += __shfl_xor(part[q], m, 64);
    if (hg == 0) {
        float eb = e2b[0];
        for (int q = 0; q < 4; q++) {
            int e = e0 + eg * 4 + q;
            float pv = part[q] + eb;
            pred_edge[e] = pv;
            atomicAdd(&flow[ei[EE + e]], pv);
        }
    }
}

// Node MLP: one wave per node, lane j = hidden unit j
__global__ __launch_bounds__(256) void k_node(const float* __restrict__ emb,
                                              const float* __restrict__ flow,
                                              const float* __restrict__ p1W,
                                              const float* __restrict__ p1b,
                                              const float* __restrict__ p2W,
                                              const float* __restrict__ p2b,
                                              float* __restrict__ out) {
    int w = threadIdx.x >> 6, j = threadIdx.x & 63;
    int n = blockIdx.x * 4 + w;
    if (n >= NN) return;
    const float* wrow = p1W + j * 65;
    const float* ev = emb + (size_t)n * 64;
    float acc = p1b[j];
    for (int f = 0; f < 64; f++) acc += wrow[f] * ev[f];
    acc += wrow[64] * flow[n];
    float val = p2W[j] * fmaxf(acc, 0.f);
    for (int m = 1; m < 64; m <<= 1) val += __shfl_xor(val, m, 64);
    if (j == 0) out[n] = val + p2b[0];
}

extern "C" void kernel_launch(void* const* d_in, const int* in_sizes, int n_in,
                              void* d_out, int out_size, void* d_ws, size_t ws_size,
                              hipStream_t stream) {
    (void)in_sizes; (void)n_in; (void)out_size; (void)ws_size;
    const float* x    = (const float*)d_in[0];
    const float* ea   = (const float*)d_in[1];
    const float* gcnW = (const float*)d_in[2];
    const float* gcnb = (const float*)d_in[3];
    const float* Wih  = (const float*)d_in[4];
    const float* Whh  = (const float*)d_in[5];
    const float* bih  = (const float*)d_in[6];
    const float* bhh  = (const float*)d_in[7];
    const float* e1W  = (const float*)d_in[8];
    const float* e1b  = (const float*)d_in[9];
    const float* e2W  = (const float*)d_in[10];
    const float* e2b  = (const float*)d_in[11];
    const float* p1W  = (const float*)d_in[12];
    const float* p1b  = (const float*)d_in[13];
    const float* p2W  = (const float*)d_in[14];
    const float* p2b  = (const float*)d_in[15];
    const int*   ei   = (const int*)d_in[16];

    char* ws = (char*)d_ws;
    float* dinv  = (float*)(ws + WS_DINV);
    float* snorm = (float*)(ws + WS_SNORM);
    float* flow  = (float*)(ws + WS_FLOW);
    float* wc    = (float*)(ws + WS_WC);
    float* bc    = (float*)(ws + WS_BC);
    float* wb    = (float*)(ws + WS_WB);
    float* emb   = (float*)(ws + WS_EMB);
    float* agg   = (float*)(ws + WS_AGG);

    float* pred_node = (float*)d_out;
    float* pred_edge = (float*)d_out + NN;

    k_init<<<(NN + 255) / 256, 256, 0, stream>>>(dinv, flow);
    k_deg<<<(EE + 255) / 256, 256, 0, stream>>>(ei, dinv);
    k_dinv<<<(NN + 255) / 256, 256, 0, stream>>>(dinv, snorm);
    k_prep<<<13, 256, 0, stream>>>(Wih, bih, gcnW, gcnb, wc, bc, wb);
    k_selfagg<<<(NN * TT + 255) / 256, 256, 0, stream>>>(x, dinv, agg);
    k_scatter<<<dim3((EE + 255) / 256, TT), 256, 0, stream>>>(x, ei, dinv, agg, snorm);
    k_gru<<<(NN + 4 * NB - 1) / (4 * NB), 256, 0, stream>>>(agg, snorm, wc, bc, wb, Whh, bhh, emb);
    k_edge<<<EE / 64, 256, 0, stream>>>(emb, ea, ei, e1W, e1b, e2W, e2b, pred_edge, flow);
    k_node<<<(NN + 3) / 4, 256, 0, stream>>>(emb, flow, p1W, p1b, p2W, p2b, pred_node);
}

// Round 2
// 2991.297 us; speedup vs baseline: 4.4505x; 4.4505x over previous
//
#include <hip/hip_runtime.h>
#include <hip/hip_bf16.h>

// Problem constants (fixed by the reference)
#define NN 50000
#define TT 16
#define FIN 16
#define GH 64     // GCN_H == GRU_H == 64
#define EH 128    // EDGE_H
#define EE 800000

// ---------------- ws layout (bytes) ----------------
#define WS_DINV  0          // N f32 (holds deg counts first, then dinv)
#define WS_SNORM 200704     // N f32
#define WS_FLOW  401408     // N f32
#define WS_WC    602112     // 192*16 f32 packed [f4][192] float4
#define WS_BC    614400     // 192 f32
#define WS_WB    615168     // 192 f32
#define WS_EMB   616192     // N*64 f32
#define WS_AGG   13416192   // N*T*16 f32, layout [n][t][16]
#define WS_OFF   64616192   // (N+1) i32
#define WS_CUR   64817152   // N i32
#define WS_ROWV  65017856   // EE i32
#define WS_NRMV  68217856   // EE f32
// total ~71.5 MB

__global__ __launch_bounds__(256) void k_init(float* deg, float* flow) {
    int n = blockIdx.x * 256 + threadIdx.x;
    if (n < NN) { deg[n] = 1.0f; flow[n] = 0.0f; }
}

__global__ __launch_bounds__(256) void k_deg(const int* __restrict__ ei, float* deg) {
    int e = blockIdx.x * 256 + threadIdx.x;
    if (e < EE) atomicAdd(&deg[ei[EE + e]], 1.0f);
}

// Exclusive scan of cnt[n] = deg[n]-1 (incoming degree). Single block, 1024 thr.
__global__ __launch_bounds__(1024) void k_scan(const float* __restrict__ deg,
                                               int* __restrict__ off,
                                               int* __restrict__ cursor) {
    __shared__ int wsum[16];
    __shared__ int carryS;
    int tid = threadIdx.x, lane = tid & 63, wv = tid >> 6;
    if (tid == 0) carryS = 0;
    __syncthreads();
    for (int base = 0; base < NN; base += 4096) {
        int i0 = base + tid * 4;
        int v[4];
        int tot = 0;
        for (int q = 0; q < 4; q++) {
            int i = i0 + q;
            v[q] = (i < NN) ? (int)deg[i] - 1 : 0;
            tot += v[q];
        }
        int inc = tot;
        for (int d = 1; d < 64; d <<= 1) {
            int tpl = __shfl_up(inc, d, 64);
            if (lane >= d) inc += tpl;
        }
        if (lane == 63) wsum[wv] = inc;
        __syncthreads();
        int wexcl = 0;
        for (int k = 0; k < 16; k++) wexcl += (k < wv) ? wsum[k] : 0;
        int run = carryS + wexcl + inc - tot;
        __syncthreads();
        for (int q = 0; q < 4; q++) {
            int i = i0 + q;
            if (i < NN) { off[i] = run; cursor[i] = run; }
            run += v[q];
        }
        if (tid == 1023) carryS = run;
        __syncthreads();
    }
    if (threadIdx.x == 0) off[NN] = carryS;
}

__global__ __launch_bounds__(256) void k_dinv(float* deg_dinv, float* snorm) {
    int n = blockIdx.x * 256 + threadIdx.x;
    if (n < NN) {
        float d = rsqrtf(deg_dinv[n]);
        deg_dinv[n] = d;
        snorm[n] = d * d;   // self-loop norm contribution
    }
}

// Fill CSR buckets: rowv/nrmv per destination; accumulate snorm.
__global__ __launch_bounds__(256) void k_fill(const int* __restrict__ ei,
                                              const float* __restrict__ dinv,
                                              int* __restrict__ cursor,
                                              int* __restrict__ rowv,
                                              float* __restrict__ nrmv,
                                              float* __restrict__ snorm) {
    int e = blockIdx.x * 256 + threadIdx.x;
    if (e >= EE) return;
    int r = ei[e], c = ei[EE + e];
    float nrm = dinv[r] * dinv[c];
    int p = atomicAdd(&cursor[c], 1);
    rowv[p] = r;
    nrmv[p] = nrm;
    atomicAdd(&snorm[c], nrm);
}

// Wc = W_ih @ gcn_W  (192x16, packed [f4][192] float4), wb = W_ih @ gcn_b, bc = b_ih
__global__ __launch_bounds__(256) void k_prep(const float* __restrict__ Wih,
                                              const float* __restrict__ bih,
                                              const float* __restrict__ gcnW,
                                              const float* __restrict__ gcnb,
                                              float* wc, float* bc, float* wb) {
    int tid = blockIdx.x * 256 + threadIdx.x;
    if (tid < 3072) {
        int f = tid & 15, row = tid >> 4;
        float s = 0.f;
        for (int k = 0; k < 64; k++) s += Wih[row * 64 + k] * gcnW[k * 16 + f];
        wc[((f >> 2) * 192 + row) * 4 + (f & 3)] = s;
    } else if (tid < 3264) {
        int row = tid - 3072;
        float s = 0.f;
        for (int k = 0; k < 64; k++) s += Wih[row * 64 + k] * gcnb[k];
        wb[row] = s;
        bc[row] = bih[row];
    }
}

// Gather: one wave per node; lane = (t = lane>>2, f4 = lane&3).
// Each lane accumulates one float4 of the node's [T][16] agg block.
__global__ __launch_bounds__(256) void k_gather(const float* __restrict__ x,
                                                const float* __restrict__ dinv,
                                                const int* __restrict__ off,
                                                const int* __restrict__ rowv,
                                                const float* __restrict__ nrmv,
                                                float* __restrict__ agg) {
    int wv = threadIdx.x >> 6, lane = threadIdx.x & 63;
    int n = blockIdx.x * 4 + wv;
    if (n >= NN) return;
    int t = lane >> 2, f4 = lane & 3;
    int s = off[n], e = off[n + 1];
    size_t toff = ((size_t)t * NN) * 16 + f4 * 4;
    float4 acc = make_float4(0.f, 0.f, 0.f, 0.f);
    int i = s;
    for (; i + 1 < e; i += 2) {
        int r0 = rowv[i],     r1 = rowv[i + 1];
        float m0 = nrmv[i],   m1 = nrmv[i + 1];
        float4 v0 = *(const float4*)(x + toff + (size_t)r0 * 16);
        float4 v1 = *(const float4*)(x + toff + (size_t)r1 * 16);
        acc.x += m0 * v0.x; acc.y += m0 * v0.y; acc.z += m0 * v0.z; acc.w += m0 * v0.w;
        acc.x += m1 * v1.x; acc.y += m1 * v1.y; acc.z += m1 * v1.z; acc.w += m1 * v1.w;
    }
    if (i < e) {
        int r0 = rowv[i];
        float m0 = nrmv[i];
        float4 v0 = *(const float4*)(x + toff + (size_t)r0 * 16);
        acc.x += m0 * v0.x; acc.y += m0 * v0.y; acc.z += m0 * v0.z; acc.w += m0 * v0.w;
    }
    float d = dinv[n], d2 = d * d;
    float4 vs = *(const float4*)(x + toff + (size_t)n * 16);
    acc.x += d2 * vs.x; acc.y += d2 * vs.y; acc.z += d2 * vs.z; acc.w += d2 * vs.w;
    ((float4*)(agg + (size_t)n * 256))[lane] = acc;
}

// Fused GCN-transform + GRU over T. 4 waves/block, NB nodes per wave.
#define NB 8
__global__ __launch_bounds__(256) void k_gru(const float* __restrict__ agg,
                                             const float* __restrict__ snorm,
                                             const float* __restrict__ wcP,
                                             const float* __restrict__ bc,
                                             const float* __restrict__ wb,
                                             const float* __restrict__ whh,
                                             const float* __restrict__ bhh,
                                             float* __restrict__ emb) {
    __shared__ float4 sWhh[16][192];       // [k4][row] = W_hh[row][4k4..4k4+3]
    __shared__ float4 sHs[4][NB][16];      // per-wave hidden state, float4 over k
    int tid = threadIdx.x;
    for (int i = tid; i < 3072; i += 256) {
        int k4 = i / 192, row = i % 192;
        const float* p = whh + row * 64 + k4 * 4;
        sWhh[k4][row] = make_float4(p[0], p[1], p[2], p[3]);
    }
    int w = tid >> 6, j = tid & 63;
    float4 wcR[3][4];
    float bcR[3], wbR[3], bhhR[3];
    for (int g = 0; g < 3; g++) {
        for (int f4 = 0; f4 < 4; f4++)
            wcR[g][f4] = ((const float4*)wcP)[f4 * 192 + g * 64 + j];
        bcR[g]  = bc[g * 64 + j];
        wbR[g]  = wb[g * 64 + j];
        bhhR[g] = bhh[g * 64 + j];
    }
    int base = blockIdx.x * (4 * NB) + w * NB;
    float hsreg[NB];
    float snr[NB];
    int nidx[NB];
    for (int m = 0; m < NB; m++) {
        int n = base + m;
        nidx[m] = (n < NN) ? n : (NN - 1);
        snr[m] = snorm[nidx[m]];
        hsreg[m] = 0.f;
        ((float*)&sHs[w][m][0])[j] = 0.f;
    }
    __syncthreads();

    for (int t = 0; t < TT; t++) {
        float gi[NB][3], gh[NB][3];
        for (int m = 0; m < NB; m++) {
            const float4* a4 = (const float4*)(agg + ((size_t)nidx[m] * 16 + t) * 16);
            gi[m][0] = bcR[0] + snr[m] * wbR[0];
            gi[m][1] = bcR[1] + snr[m] * wbR[1];
            gi[m][2] = bcR[2] + snr[m] * wbR[2];
            for (int f4 = 0; f4 < 4; f4++) {
                float4 av = a4[f4];
                for (int g = 0; g < 3; g++) {
                    gi[m][g] += wcR[g][f4].x * av.x + wcR[g][f4].y * av.y
                              + wcR[g][f4].z * av.z + wcR[g][f4].w * av.w;
                }
            }
            gh[m][0] = bhhR[0]; gh[m][1] = bhhR[1]; gh[m][2] = bhhR[2];
        }
        for (int k4 = 0; k4 < 16; k4++) {
            float4 w0 = sWhh[k4][j];
            float4 w1 = sWhh[k4][64 + j];
            float4 w2 = sWhh[k4][128 + j];
            for (int m = 0; m < NB; m++) {
                float4 h4 = sHs[w][m][k4];
                gh[m][0] += w0.x * h4.x + w0.y * h4.y + w0.z * h4.z + w0.w * h4.w;
                gh[m][1] += w1.x * h4.x + w1.y * h4.y + w1.z * h4.z + w1.w * h4.w;
                gh[m][2] += w2.x * h4.x + w2.y * h4.y + w2.z * h4.z + w2.w * h4.w;
            }
        }
        __syncthreads();
        for (int m = 0; m < NB; m++) {
            float r = 1.f / (1.f + __expf(-(gi[m][0] + gh[m][0])));
            float z = 1.f / (1.f + __expf(-(gi[m][1] + gh[m][1])));
            float a = gi[m][2] + r * gh[m][2];
            a = fminf(fmaxf(a, -15.f), 15.f);
            float e2 = __expf(2.f * a);
            float nn = (e2 - 1.f) / (e2 + 1.f);
            hsreg[m] = (1.f - z) * nn + z * hsreg[m];
            ((float*)&sHs[w][m][0])[j] = hsreg[m];
        }
        __syncthreads();
    }
    for (int m = 0; m < NB; m++) {
        int n = base + m;
        if (n < NN) emb[(size_t)n * 64 + j] = hsreg[m];
    }
}

// Edge MLP: per wave 16 edges; lane = eg(4 groups of 4 edges) x hg(16 groups of 8 hidden)
__global__ __launch_bounds__(256) void k_edge(const float* __restrict__ emb,
                                              const float* __restrict__ ea,
                                              const int* __restrict__ ei,
                                              const float* __restrict__ e1W,
                                              const float* __restrict__ e1b,
                                              const float* __restrict__ e2W,
                                              const float* __restrict__ e2b,
                                              float* __restrict__ pred_edge,
                                              float* __restrict__ flow) {
    __shared__ float4 sIn[4][16 * 33];   // per wave: 16 edges x 33 float4 (132 f32)
    int tid = threadIdx.x;
    int w = tid >> 6, l = tid & 63;
    int e0 = (blockIdx.x * 4 + w) * 16;
    for (int i = l; i < 528; i += 64) {
        int ed = i / 33, comp = i - ed * 33;
        int e = e0 + ed;
        float4 v;
        if (comp < 16) {
            int r = ei[e];
            v = ((const float4*)(emb + (size_t)r * 64))[comp];
        } else if (comp < 32) {
            int c = ei[EE + e];
            v = ((const float4*)(emb + (size_t)c * 64))[comp - 16];
        } else {
            v = ((const float4*)ea)[e];
        }
        sIn[w][ed * 33 + comp] = v;
    }
    __syncthreads();
    int hg = l & 15, eg = l >> 4;
    float acc[4][8];
    for (int q = 0; q < 4; q++)
        for (int hh = 0; hh < 8; hh++) acc[q][hh] = 0.f;
    const float* wbase = e1W + (size_t)(hg * 8) * 132;
    for (int k4 = 0; k4 < 33; k4++) {
        float4 wv[8];
        for (int hh = 0; hh < 8; hh++)
            wv[hh] = *(const float4*)(wbase + hh * 132 + k4 * 4);
        for (int q = 0; q < 4; q++) {
            float4 iv = sIn[w][(eg * 4 + q) * 33 + k4];
            for (int hh = 0; hh < 8; hh++)
                acc[q][hh] += wv[hh].x * iv.x + wv[hh].y * iv.y
                            + wv[hh].z * iv.z + wv[hh].w * iv.w;
        }
    }
    float4 b1a = ((const float4*)e1b)[hg * 2], b1b = ((const float4*)e1b)[hg * 2 + 1];
    float4 w2a = ((const float4*)e2W)[hg * 2], w2b = ((const float4*)e2W)[hg * 2 + 1];
    float part[4];
    for (int q = 0; q < 4; q++) {
        float s = 0.f;
        s += w2a.x * fmaxf(acc[q][0] + b1a.x, 0.f);
        s += w2a.y * fmaxf(acc[q][1] + b1a.y, 0.f);
        s += w2a.z * fmaxf(acc[q][2] + b1a.z, 0.f);
        s += w2a.w * fmaxf(acc[q][3] + b1a.w, 0.f);
        s += w2b.x * fmaxf(acc[q][4] + b1b.x, 0.f);
        s += w2b.y * fmaxf(acc[q][5] + b1b.y, 0.f);
        s += w2b.z * fmaxf(acc[q][6] + b1b.z, 0.f);
        s += w2b.w * fmaxf(acc[q][7] + b1b.w, 0.f);
        part[q] = s;
    }
    for (int m = 1; m < 16; m <<= 1)
        for (int q = 0; q < 4; q++) part[q] += __shfl_xor(part[q], m, 64);
    if (hg == 0) {
        float eb = e2b[0];
        for (int q = 0; q < 4; q++) {
            int e = e0 + eg * 4 + q;
            float pv = part[q] + eb;
            pred_edge[e] = pv;
            atomicAdd(&flow[ei[EE + e]], pv);
        }
    }
}

// Node MLP: one wave per node, lane j = hidden unit j
__global__ __launch_bounds__(256) void k_node(const float* __restrict__ emb,
                                              const float* __restrict__ flow,
                                              const float* __restrict__ p1W,
                                              const float* __restrict__ p1b,
                                              const float* __restrict__ p2W,
                                              const float* __restrict__ p2b,
                                              float* __restrict__ out) {
    int w = threadIdx.x >> 6, j = threadIdx.x & 63;
    int n = blockIdx.x * 4 + w;
    if (n >= NN) return;
    const float* wrow = p1W + j * 65;
    const float* ev = emb + (size_t)n * 64;
    float acc = p1b[j];
    for (int f = 0; f < 64; f++) acc += wrow[f] * ev[f];
    acc += wrow[64] * flow[n];
    float val = p2W[j] * fmaxf(acc, 0.f);
    for (int m = 1; m < 64; m <<= 1) val += __shfl_xor(val, m, 64);
    if (j == 0) out[n] = val + p2b[0];
}

extern "C" void kernel_launch(void* const* d_in, const int* in_sizes, int n_in,
                              void* d_out, int out_size, void* d_ws, size_t ws_size,
                              hipStream_t stream) {
    (void)in_sizes; (void)n_in; (void)out_size; (void)ws_size;
    const float* x    = (const float*)d_in[0];
    const float* ea   = (const float*)d_in[1];
    const float* gcnW = (const float*)d_in[2];
    const float* gcnb = (const float*)d_in[3];
    const float* Wih  = (const float*)d_in[4];
    const float* Whh  = (const float*)d_in[5];
    const float* bih  = (const float*)d_in[6];
    const float* bhh  = (const float*)d_in[7];
    const float* e1W  = (const float*)d_in[8];
    const float* e1b  = (const float*)d_in[9];
    const float* e2W  = (const float*)d_in[10];
    const float* e2b  = (const float*)d_in[11];
    const float* p1W  = (const float*)d_in[12];
    const float* p1b  = (const float*)d_in[13];
    const float* p2W  = (const float*)d_in[14];
    const float* p2b  = (const float*)d_in[15];
    const int*   ei   = (const int*)d_in[16];

    char* ws = (char*)d_ws;
    float* dinv  = (float*)(ws + WS_DINV);
    float* snorm = (float*)(ws + WS_SNORM);
    float* flow  = (float*)(ws + WS_FLOW);
    float* wc    = (float*)(ws + WS_WC);
    float* bc    = (float*)(ws + WS_BC);
    float* wb    = (float*)(ws + WS_WB);
    float* emb   = (float*)(ws + WS_EMB);
    float* agg   = (float*)(ws + WS_AGG);
    int*   off   = (int*)(ws + WS_OFF);
    int*   cur   = (int*)(ws + WS_CUR);
    int*   rowv  = (int*)(ws + WS_ROWV);
    float* nrmv  = (float*)(ws + WS_NRMV);

    float* pred_node = (float*)d_out;
    float* pred_edge = (float*)d_out + NN;

    k_init<<<(NN + 255) / 256, 256, 0, stream>>>(dinv, flow);
    k_deg<<<(EE + 255) / 256, 256, 0, stream>>>(ei, dinv);
    k_scan<<<1, 1024, 0, stream>>>(dinv, off, cur);
    k_dinv<<<(NN + 255) / 256, 256, 0, stream>>>(dinv, snorm);
    k_prep<<<13, 256, 0, stream>>>(Wih, bih, gcnW, gcnb, wc, bc, wb);
    k_fill<<<(EE + 255) / 256, 256, 0, stream>>>(ei, dinv, cur, rowv, nrmv, snorm);
    k_gather<<<(NN + 3) / 4, 256, 0, stream>>>(x, dinv, off, rowv, nrmv, agg);
    k_gru<<<(NN + 4 * NB - 1) / (4 * NB), 256, 0, stream>>>(agg, snorm, wc, bc, wb, Whh, bhh, emb);
    k_edge<<<EE / 64, 256, 0, stream>>>(emb, ea, ei, e1W, e1b, e2W, e2b, pred_edge, flow);
    k_node<<<(NN + 3) / 4, 256, 0, stream>>>(emb, flow, p1W, p1b, p2W, p2b, pred_node);
}

// Round 3
// 1748.015 us; speedup vs baseline: 7.6160x; 1.7113x over previous
//
#include <hip/hip_runtime.h>
#include <hip/hip_bf16.h>

// Problem constants (fixed by the reference)
#define NN 50000
#define TT 16
#define FIN 16
#define GH 64     // GCN_H == GRU_H == 64
#define EH 128    // EDGE_H
#define EE 800000

typedef __attribute__((ext_vector_type(8))) short short8;
typedef __attribute__((ext_vector_type(4))) float f32x4;

// ---------------- ws layout (bytes) ----------------
#define WS_DINV  0          // N f32 (holds deg counts first, then dinv)
#define WS_SNORM 200704     // N f32
#define WS_FLOW  401408     // N f32
#define WS_WC    602112     // 192*16 f32 packed [f4][192] float4
#define WS_BC    614400     // 192 f32
#define WS_WB    615168     // 192 f32
#define WS_EMB   616192     // N*64 f32
#define WS_AGG   13416192   // N*T*16 f32, layout [n][t][16] (51.2 MB, dead after k_gru)
// bf16 hi/lo copies overlay the agg region (written after k_gru consumes agg):
#define WS_EMBH  13416192   // N*64 ushort (6.4 MB)
#define WS_EMBL  19816192   // N*64 ushort
#define WS_EAH   26216192   // E*4 ushort
#define WS_EAL   32616192   // E*4 ushort
#define WS_OFF   64616192   // (N+1) i32
#define WS_CUR   64817152   // N i32
#define WS_ROWV  65017856   // EE i32
#define WS_NRMV  68217856   // EE f32
#define WS_WPH   71417856   // 128*160 ushort (padded e1W hi)
#define WS_WPL   71458816   // 128*160 ushort (padded e1W lo)
#define WS_B1W2  71499776   // 128 float2 (e1b, e2W)
// total ~71.6 MB

static __device__ inline ushort f2bf(float v) {
    __hip_bfloat16 b = __float2bfloat16(v);
    return *(ushort*)&b;
}
static __device__ inline float bf2f(ushort u) {
    __hip_bfloat16 b; *(ushort*)&b = u;
    return __bfloat162float(b);
}

__global__ __launch_bounds__(256) void k_init(float* deg, float* flow) {
    int n = blockIdx.x * 256 + threadIdx.x;
    if (n < NN) { deg[n] = 1.0f; flow[n] = 0.0f; }
}

__global__ __launch_bounds__(256) void k_deg(const int* __restrict__ ei, float* deg) {
    int e = blockIdx.x * 256 + threadIdx.x;
    if (e < EE) atomicAdd(&deg[ei[EE + e]], 1.0f);
}

// Exclusive scan of cnt[n] = deg[n]-1 (incoming degree). Single block, 1024 thr.
__global__ __launch_bounds__(1024) void k_scan(const float* __restrict__ deg,
                                               int* __restrict__ off,
                                               int* __restrict__ cursor) {
    __shared__ int wsum[16];
    __shared__ int carryS;
    int tid = threadIdx.x, lane = tid & 63, wv = tid >> 6;
    if (tid == 0) carryS = 0;
    __syncthreads();
    for (int base = 0; base < NN; base += 4096) {
        int i0 = base + tid * 4;
        int v[4];
        int tot = 0;
        for (int q = 0; q < 4; q++) {
            int i = i0 + q;
            v[q] = (i < NN) ? (int)deg[i] - 1 : 0;
            tot += v[q];
        }
        int inc = tot;
        for (int d = 1; d < 64; d <<= 1) {
            int tpl = __shfl_up(inc, d, 64);
            if (lane >= d) inc += tpl;
        }
        if (lane == 63) wsum[wv] = inc;
        __syncthreads();
        int wexcl = 0;
        for (int k = 0; k < 16; k++) wexcl += (k < wv) ? wsum[k] : 0;
        int run = carryS + wexcl + inc - tot;
        __syncthreads();
        for (int q = 0; q < 4; q++) {
            int i = i0 + q;
            if (i < NN) { off[i] = run; cursor[i] = run; }
            run += v[q];
        }
        if (tid == 1023) carryS = run;
        __syncthreads();
    }
    if (threadIdx.x == 0) off[NN] = carryS;
}

__global__ __launch_bounds__(256) void k_dinv(float* deg_dinv, float* snorm) {
    int n = blockIdx.x * 256 + threadIdx.x;
    if (n < NN) {
        float d = rsqrtf(deg_dinv[n]);
        deg_dinv[n] = d;
        snorm[n] = d * d;   // self-loop norm contribution
    }
}

// Fill CSR buckets: rowv/nrmv per destination; accumulate snorm.
__global__ __launch_bounds__(256) void k_fill(const int* __restrict__ ei,
                                              const float* __restrict__ dinv,
                                              int* __restrict__ cursor,
                                              int* __restrict__ rowv,
                                              float* __restrict__ nrmv,
                                              float* __restrict__ snorm) {
    int e = blockIdx.x * 256 + threadIdx.x;
    if (e >= EE) return;
    int r = ei[e], c = ei[EE + e];
    float nrm = dinv[r] * dinv[c];
    int p = atomicAdd(&cursor[c], 1);
    rowv[p] = r;
    nrmv[p] = nrm;
    atomicAdd(&snorm[c], nrm);
}

// Wc = W_ih @ gcn_W  (192x16, packed [f4][192] float4), wb = W_ih @ gcn_b, bc = b_ih
__global__ __launch_bounds__(256) void k_prep(const float* __restrict__ Wih,
                                              const float* __restrict__ bih,
                                              const float* __restrict__ gcnW,
                                              const float* __restrict__ gcnb,
                                              float* wc, float* bc, float* wb) {
    int tid = blockIdx.x * 256 + threadIdx.x;
    if (tid < 3072) {
        int f = tid & 15, row = tid >> 4;
        float s = 0.f;
        for (int k = 0; k < 64; k++) s += Wih[row * 64 + k] * gcnW[k * 16 + f];
        wc[((f >> 2) * 192 + row) * 4 + (f & 3)] = s;
    } else if (tid < 3264) {
        int row = tid - 3072;
        float s = 0.f;
        for (int k = 0; k < 64; k++) s += Wih[row * 64 + k] * gcnb[k];
        wb[row] = s;
        bc[row] = bih[row];
    }
}

// Padded bf16 hi/lo copy of e1W ([128][160], k>=132 zero) + (e1b,e2W) float2 table.
__global__ __launch_bounds__(256) void k_prepw(const float* __restrict__ e1W,
                                               const float* __restrict__ e1b,
                                               const float* __restrict__ e2W,
                                               ushort* __restrict__ wph,
                                               ushort* __restrict__ wpl,
                                               float2* __restrict__ b1w2) {
    int idx = blockIdx.x * 256 + threadIdx.x;
    if (idx < 20480) {
        int h = idx / 160, k = idx - h * 160;
        float v = (k < 132) ? e1W[h * 132 + k] : 0.f;
        ushort hb = f2bf(v);
        wph[idx] = hb;
        wpl[idx] = f2bf(v - bf2f(hb));
    } else if (idx < 20608) {
        int h = idx - 20480;
        b1w2[h] = make_float2(e1b[h], e2W[h]);
    }
}

// Gather: one wave per node; lane = (t = lane>>2, f4 = lane&3).
__global__ __launch_bounds__(256) void k_gather(const float* __restrict__ x,
                                                const float* __restrict__ dinv,
                                                const int* __restrict__ off,
                                                const int* __restrict__ rowv,
                                                const float* __restrict__ nrmv,
                                                float* __restrict__ agg) {
    int wv = threadIdx.x >> 6, lane = threadIdx.x & 63;
    int n = blockIdx.x * 4 + wv;
    if (n >= NN) return;
    int t = lane >> 2, f4 = lane & 3;
    int s = off[n], e = off[n + 1];
    size_t toff = ((size_t)t * NN) * 16 + f4 * 4;
    float4 acc = make_float4(0.f, 0.f, 0.f, 0.f);
    int i = s;
    for (; i + 1 < e; i += 2) {
        int r0 = rowv[i],     r1 = rowv[i + 1];
        float m0 = nrmv[i],   m1 = nrmv[i + 1];
        float4 v0 = *(const float4*)(x + toff + (size_t)r0 * 16);
        float4 v1 = *(const float4*)(x + toff + (size_t)r1 * 16);
        acc.x += m0 * v0.x; acc.y += m0 * v0.y; acc.z += m0 * v0.z; acc.w += m0 * v0.w;
        acc.x += m1 * v1.x; acc.y += m1 * v1.y; acc.z += m1 * v1.z; acc.w += m1 * v1.w;
    }
    if (i < e) {
        int r0 = rowv[i];
        float m0 = nrmv[i];
        float4 v0 = *(const float4*)(x + toff + (size_t)r0 * 16);
        acc.x += m0 * v0.x; acc.y += m0 * v0.y; acc.z += m0 * v0.z; acc.w += m0 * v0.w;
    }
    float d = dinv[n], d2 = d * d;
    float4 vs = *(const float4*)(x + toff + (size_t)n * 16);
    acc.x += d2 * vs.x; acc.y += d2 * vs.y; acc.z += d2 * vs.z; acc.w += d2 * vs.w;
    ((float4*)(agg + (size_t)n * 256))[lane] = acc;
}

// Fused GCN-transform + GRU over T. 4 waves/block, NB nodes per wave.
#define NB 8
__global__ __launch_bounds__(256) void k_gru(const float* __restrict__ agg,
                                             const float* __restrict__ snorm,
                                             const float* __restrict__ wcP,
                                             const float* __restrict__ bc,
                                             const float* __restrict__ wb,
                                             const float* __restrict__ whh,
                                             const float* __restrict__ bhh,
                                             float* __restrict__ emb) {
    __shared__ float4 sWhh[16][192];       // [k4][row] = W_hh[row][4k4..4k4+3]
    __shared__ float4 sHs[4][NB][16];      // per-wave hidden state, float4 over k
    int tid = threadIdx.x;
    for (int i = tid; i < 3072; i += 256) {
        int k4 = i / 192, row = i % 192;
        const float* p = whh + row * 64 + k4 * 4;
        sWhh[k4][row] = make_float4(p[0], p[1], p[2], p[3]);
    }
    int w = tid >> 6, j = tid & 63;
    float4 wcR[3][4];
    float bcR[3], wbR[3], bhhR[3];
    for (int g = 0; g < 3; g++) {
        for (int f4 = 0; f4 < 4; f4++)
            wcR[g][f4] = ((const float4*)wcP)[f4 * 192 + g * 64 + j];
        bcR[g]  = bc[g * 64 + j];
        wbR[g]  = wb[g * 64 + j];
        bhhR[g] = bhh[g * 64 + j];
    }
    int base = blockIdx.x * (4 * NB) + w * NB;
    float hsreg[NB];
    float snr[NB];
    int nidx[NB];
    for (int m = 0; m < NB; m++) {
        int n = base + m;
        nidx[m] = (n < NN) ? n : (NN - 1);
        snr[m] = snorm[nidx[m]];
        hsreg[m] = 0.f;
        ((float*)&sHs[w][m][0])[j] = 0.f;
    }
    __syncthreads();

    for (int t = 0; t < TT; t++) {
        float gi[NB][3], gh[NB][3];
        for (int m = 0; m < NB; m++) {
            const float4* a4 = (const float4*)(agg + ((size_t)nidx[m] * 16 + t) * 16);
            gi[m][0] = bcR[0] + snr[m] * wbR[0];
            gi[m][1] = bcR[1] + snr[m] * wbR[1];
            gi[m][2] = bcR[2] + snr[m] * wbR[2];
            for (int f4 = 0; f4 < 4; f4++) {
                float4 av = a4[f4];
                for (int g = 0; g < 3; g++) {
                    gi[m][g] += wcR[g][f4].x * av.x + wcR[g][f4].y * av.y
                              + wcR[g][f4].z * av.z + wcR[g][f4].w * av.w;
                }
            }
            gh[m][0] = bhhR[0]; gh[m][1] = bhhR[1]; gh[m][2] = bhhR[2];
        }
        for (int k4 = 0; k4 < 16; k4++) {
            float4 w0 = sWhh[k4][j];
            float4 w1 = sWhh[k4][64 + j];
            float4 w2 = sWhh[k4][128 + j];
            for (int m = 0; m < NB; m++) {
                float4 h4 = sHs[w][m][k4];
                gh[m][0] += w0.x * h4.x + w0.y * h4.y + w0.z * h4.z + w0.w * h4.w;
                gh[m][1] += w1.x * h4.x + w1.y * h4.y + w1.z * h4.z + w1.w * h4.w;
                gh[m][2] += w2.x * h4.x + w2.y * h4.y + w2.z * h4.z + w2.w * h4.w;
            }
        }
        __syncthreads();
        for (int m = 0; m < NB; m++) {
            float r = 1.f / (1.f + __expf(-(gi[m][0] + gh[m][0])));
            float z = 1.f / (1.f + __expf(-(gi[m][1] + gh[m][1])));
            float a = gi[m][2] + r * gh[m][2];
            a = fminf(fmaxf(a, -15.f), 15.f);
            float e2 = __expf(2.f * a);
            float nn = (e2 - 1.f) / (e2 + 1.f);
            hsreg[m] = (1.f - z) * nn + z * hsreg[m];
            ((float*)&sHs[w][m][0])[j] = hsreg[m];
        }
        __syncthreads();
    }
    for (int m = 0; m < NB; m++) {
        int n = base + m;
        if (n < NN) emb[(size_t)n * 64 + j] = hsreg[m];
    }
}

// Convert emb (N*64 = 3.2M) and ea (E*4 = 3.2M) to bf16 hi/lo.
__global__ __launch_bounds__(256) void k_cvt(const float* __restrict__ emb,
                                             const float* __restrict__ ea,
                                             ushort* __restrict__ embh,
                                             ushort* __restrict__ embl,
                                             ushort* __restrict__ eah,
                                             ushort* __restrict__ eal) {
    int i = blockIdx.x * 256 + threadIdx.x;
    if (i >= 3200000) return;
    float v = emb[i];
    ushort hb = f2bf(v);
    embh[i] = hb;
    embl[i] = f2bf(v - bf2f(hb));
    float u = ea[i];
    ushort hb2 = f2bf(u);
    eah[i] = hb2;
    eal[i] = f2bf(u - bf2f(hb2));
}

// Edge MLP via MFMA, bf16 hi/lo split (3 passes = f32-accurate).
// Block = 4 waves; each wave owns 32 edges (2 subtiles of 16).
// A = [emb[row] | emb[col] | ea | 0-pad] : K = 160 = 5 ksteps of 32.
__global__ __launch_bounds__(256) void k_edge(const ushort* __restrict__ embh,
                                              const ushort* __restrict__ embl,
                                              const ushort* __restrict__ eah,
                                              const ushort* __restrict__ eal,
                                              const ushort* __restrict__ wph,
                                              const ushort* __restrict__ wpl,
                                              const float2* __restrict__ b1w2,
                                              const int* __restrict__ ei,
                                              const float* __restrict__ e2b,
                                              float* __restrict__ pred_edge,
                                              float* __restrict__ flow) {
    int w = threadIdx.x >> 6, l = threadIdx.x & 63;
    int lg = l >> 4, lr = l & 15;
    int ebase = (blockIdx.x * 4 + w) * 32;

    // A-fragments: lane supplies row (lr) of each 16-edge subtile, k = ks*32 + lg*8 + [0..8)
    short8 Ah[2][5], Al[2][5];
    for (int s = 0; s < 2; s++) {
        int e = ebase + s * 16 + lr;
        int r = ei[e], c = ei[EE + e];
        for (int ks = 0; ks < 4; ks++) {
            int src = (ks < 2) ? r : c;
            int kk = (ks & 1) * 32 + lg * 8;
            Ah[s][ks] = *(const short8*)(embh + (size_t)src * 64 + kk);
            Al[s][ks] = *(const short8*)(embl + (size_t)src * 64 + kk);
        }
        short8 zh = {0, 0, 0, 0, 0, 0, 0, 0};
        short8 zl = {0, 0, 0, 0, 0, 0, 0, 0};
        if (lg == 0) {   // k 128..131 = edge_attr, rest zero
            const uint* ph4 = (const uint*)(eah + (size_t)e * 4);
            const uint* pl4 = (const uint*)(eal + (size_t)e * 4);
            ((uint*)&zh)[0] = ph4[0]; ((uint*)&zh)[1] = ph4[1];
            ((uint*)&zl)[0] = pl4[0]; ((uint*)&zl)[1] = pl4[1];
        }
        Ah[s][4] = zh;
        Al[s][4] = zl;
    }

    float esum[2][4];
    for (int s = 0; s < 2; s++)
        for (int q = 0; q < 4; q++) esum[s][q] = 0.f;

    for (int nt = 0; nt < 8; nt++) {
        int n0 = nt * 16;
        f32x4 acc[2] = {{0.f, 0.f, 0.f, 0.f}, {0.f, 0.f, 0.f, 0.f}};
        const ushort* wbh = wph + (size_t)(n0 + lr) * 160 + lg * 8;
        const ushort* wbl = wpl + (size_t)(n0 + lr) * 160 + lg * 8;
        for (int ks = 0; ks < 5; ks++) {
            short8 bh = *(const short8*)(wbh + ks * 32);
            short8 bl = *(const short8*)(wbl + ks * 32);
            for (int s = 0; s < 2; s++) {
                acc[s] = __builtin_amdgcn_mfma_f32_16x16x32_bf16(Ah[s][ks], bh, acc[s], 0, 0, 0);
                acc[s] = __builtin_amdgcn_mfma_f32_16x16x32_bf16(Ah[s][ks], bl, acc[s], 0, 0, 0);
                acc[s] = __builtin_amdgcn_mfma_f32_16x16x32_bf16(Al[s][ks], bh, acc[s], 0, 0, 0);
            }
        }
        // C[row=lg*4+q (edge in subtile)][col=lr -> h=n0+lr]
        float2 bw = b1w2[n0 + lr];
        for (int s = 0; s < 2; s++)
            for (int q = 0; q < 4; q++)
                esum[s][q] += fmaxf(acc[s][q] + bw.x, 0.f) * bw.y;
    }
    // reduce over the 16 h-columns (lr bits = lane bits 0..3)
    for (int m = 1; m < 16; m <<= 1)
        for (int s = 0; s < 2; s++)
            for (int q = 0; q < 4; q++)
                esum[s][q] += __shfl_xor(esum[s][q], m, 64);
    if (lr == 0) {
        float eb = e2b[0];
        for (int s = 0; s < 2; s++)
            for (int q = 0; q < 4; q++) {
                int e = ebase + s * 16 + lg * 4 + q;
                float pv = esum[s][q] + eb;
                pred_edge[e] = pv;
                atomicAdd(&flow[ei[EE + e]], pv);
            }
    }
}

// Node MLP: one wave per node, lane j = hidden unit j
__global__ __launch_bounds__(256) void k_node(const float* __restrict__ emb,
                                              const float* __restrict__ flow,
                                              const float* __restrict__ p1W,
                                              const float* __restrict__ p1b,
                                              const float* __restrict__ p2W,
                                              const float* __restrict__ p2b,
                                              float* __restrict__ out) {
    int w = threadIdx.x >> 6, j = threadIdx.x & 63;
    int n = blockIdx.x * 4 + w;
    if (n >= NN) return;
    const float* wrow = p1W + j * 65;
    const float* ev = emb + (size_t)n * 64;
    float acc = p1b[j];
    for (int f = 0; f < 64; f++) acc += wrow[f] * ev[f];
    acc += wrow[64] * flow[n];
    float val = p2W[j] * fmaxf(acc, 0.f);
    for (int m = 1; m < 64; m <<= 1) val += __shfl_xor(val, m, 64);
    if (j == 0) out[n] = val + p2b[0];
}

extern "C" void kernel_launch(void* const* d_in, const int* in_sizes, int n_in,
                              void* d_out, int out_size, void* d_ws, size_t ws_size,
                              hipStream_t stream) {
    (void)in_sizes; (void)n_in; (void)out_size; (void)ws_size;
    const float* x    = (const float*)d_in[0];
    const float* ea   = (const float*)d_in[1];
    const float* gcnW = (const float*)d_in[2];
    const float* gcnb = (const float*)d_in[3];
    const float* Wih  = (const float*)d_in[4];
    const float* Whh  = (const float*)d_in[5];
    const float* bih  = (const float*)d_in[6];
    const float* bhh  = (const float*)d_in[7];
    const float* e1W  = (const float*)d_in[8];
    const float* e1b  = (const float*)d_in[9];
    const float* e2W  = (const float*)d_in[10];
    const float* e2b  = (const float*)d_in[11];
    const float* p1W  = (const float*)d_in[12];
    const float* p1b  = (const float*)d_in[13];
    const float* p2W  = (const float*)d_in[14];
    const float* p2b  = (const float*)d_in[15];
    const int*   ei   = (const int*)d_in[16];

    char* ws = (char*)d_ws;
    float*  dinv  = (float*)(ws + WS_DINV);
    float*  snorm = (float*)(ws + WS_SNORM);
    float*  flow  = (float*)(ws + WS_FLOW);
    float*  wc    = (float*)(ws + WS_WC);
    float*  bc    = (float*)(ws + WS_BC);
    float*  wb    = (float*)(ws + WS_WB);
    float*  emb   = (float*)(ws + WS_EMB);
    float*  agg   = (float*)(ws + WS_AGG);
    ushort* embh  = (ushort*)(ws + WS_EMBH);
    ushort* embl  = (ushort*)(ws + WS_EMBL);
    ushort* eah   = (ushort*)(ws + WS_EAH);
    ushort* eal   = (ushort*)(ws + WS_EAL);
    int*    off   = (int*)(ws + WS_OFF);
    int*    cur   = (int*)(ws + WS_CUR);
    int*    rowv  = (int*)(ws + WS_ROWV);
    float*  nrmv  = (float*)(ws + WS_NRMV);
    ushort* wph   = (ushort*)(ws + WS_WPH);
    ushort* wpl   = (ushort*)(ws + WS_WPL);
    float2* b1w2  = (float2*)(ws + WS_B1W2);

    float* pred_node = (float*)d_out;
    float* pred_edge = (float*)d_out + NN;

    k_init<<<(NN + 255) / 256, 256, 0, stream>>>(dinv, flow);
    k_deg<<<(EE + 255) / 256, 256, 0, stream>>>(ei, dinv);
    k_scan<<<1, 1024, 0, stream>>>(dinv, off, cur);
    k_dinv<<<(NN + 255) / 256, 256, 0, stream>>>(dinv, snorm);
    k_prep<<<13, 256, 0, stream>>>(Wih, bih, gcnW, gcnb, wc, bc, wb);
    k_prepw<<<81, 256, 0, stream>>>(e1W, e1b, e2W, wph, wpl, b1w2);
    k_fill<<<(EE + 255) / 256, 256, 0, stream>>>(ei, dinv, cur, rowv, nrmv, snorm);
    k_gather<<<(NN + 3) / 4, 256, 0, stream>>>(x, dinv, off, rowv, nrmv, agg);
    k_gru<<<(NN + 4 * NB - 1) / (4 * NB), 256, 0, stream>>>(agg, snorm, wc, bc, wb, Whh, bhh, emb);
    k_cvt<<<(3200000 + 255) / 256, 256, 0, stream>>>(emb, ea, embh, embl, eah, eal);
    k_edge<<<EE / 128, 256, 0, stream>>>(embh, embl, eah, eal, wph, wpl, b1w2, ei, e2b, pred_edge, flow);
    k_node<<<(NN + 3) / 4, 256, 0, stream>>>(emb, flow, p1W, p1b, p2W, p2b, pred_node);
}

// Round 4
// 971.626 us; speedup vs baseline: 13.7017x; 1.7991x over previous
//
#include <hip/hip_runtime.h>
#include <hip/hip_bf16.h>

// Problem constants (fixed by the reference)
#define NN 50000
#define TT 16
#define FIN 16
#define GH 64     // GCN_H == GRU_H == 64
#define EH 128    // EDGE_H
#define EE 800000

typedef __attribute__((ext_vector_type(8))) short short8;
typedef __attribute__((ext_vector_type(4))) float f32x4;

// ---------------- ws layout (bytes) ----------------
#define WS_DINV  0          // N f32 (deg counts first, then dinv)
#define WS_SNORM 200704     // N f32
#define WS_FLOW  401408     // N f32
#define WS_WC    602112     // 192*16 f32 row-major Wc = Wih@gcnW
#define WS_WB    615168     // 192 f32   wb = Wih@gcnb
#define WS_EMB   616192     // N*64 f32
#define WS_AGGH  13416192   // N*T*16 ushort (25.6 MB), layout [n][t][16]
#define WS_AGGL  39016192   // N*T*16 ushort (25.6 MB)
// bf16 copies for k_edge overlay the aggh region (dead after k_gru2):
#define WS_EMBH  13416192   // N*64 ushort
#define WS_EMBL  19816192   // N*64 ushort
#define WS_EAH   26216192   // E*4 ushort
#define WS_EAL   32616192   // E*4 ushort
#define WS_OFF   64616192   // (N+1) i32
#define WS_CUR   64817152   // N i32
#define WS_ROWV  65017856   // EE i32
#define WS_NRMV  68217856   // EE f32 (dead after k_gather; tail reused below)
#define WS_PKH   68217856   // 256*96 ushort packed GRU weights hi (overlay nrmv)
#define WS_PKL   68267008   // 256*96 ushort lo
#define WS_BA    68316160   // 256 f32 biasA
#define WS_BB    68317184   // 256 f32 biasB
#define WS_WPH   71417856   // 128*160 ushort (padded e1W hi)
#define WS_WPL   71458816   // 128*160 ushort (padded e1W lo)
#define WS_B1W2  71499776   // 128 float2 (e1b, e2W)

static __device__ inline ushort f2bf(float v) {
    __hip_bfloat16 b = __float2bfloat16(v);
    return *(ushort*)&b;
}
static __device__ inline float bf2f(ushort u) {
    __hip_bfloat16 b; *(ushort*)&b = u;
    return __bfloat162float(b);
}
static __device__ inline f32x4 mfma3(short8 ah, short8 al, short8 bh, short8 bl, f32x4 c) {
    c = __builtin_amdgcn_mfma_f32_16x16x32_bf16(ah, bh, c, 0, 0, 0);
    c = __builtin_amdgcn_mfma_f32_16x16x32_bf16(ah, bl, c, 0, 0, 0);
    c = __builtin_amdgcn_mfma_f32_16x16x32_bf16(al, bh, c, 0, 0, 0);
    return c;
}
static __device__ inline short8 ld8u(const ushort* p) {   // 8-B aligned LDS/global read
    short8 v;
    ((uint2*)&v)[0] = *(const uint2*)p;
    ((uint2*)&v)[1] = *(const uint2*)(p + 4);
    return v;
}

__global__ __launch_bounds__(256) void k_init(float* deg, float* flow) {
    int n = blockIdx.x * 256 + threadIdx.x;
    if (n < NN) { deg[n] = 1.0f; flow[n] = 0.0f; }
}

__global__ __launch_bounds__(256) void k_deg(const int* __restrict__ ei, float* deg) {
    int e = blockIdx.x * 256 + threadIdx.x;
    if (e < EE) atomicAdd(&deg[ei[EE + e]], 1.0f);
}

// Exclusive scan of cnt[n] = deg[n]-1 (incoming degree). Single block, 1024 thr.
__global__ __launch_bounds__(1024) void k_scan(const float* __restrict__ deg,
                                               int* __restrict__ off,
                                               int* __restrict__ cursor) {
    __shared__ int wsum[16];
    __shared__ int carryS;
    int tid = threadIdx.x, lane = tid & 63, wv = tid >> 6;
    if (tid == 0) carryS = 0;
    __syncthreads();
    for (int base = 0; base < NN; base += 4096) {
        int i0 = base + tid * 4;
        int v[4];
        int tot = 0;
        for (int q = 0; q < 4; q++) {
            int i = i0 + q;
            v[q] = (i < NN) ? (int)deg[i] - 1 : 0;
            tot += v[q];
        }
        int inc = tot;
        for (int d = 1; d < 64; d <<= 1) {
            int tpl = __shfl_up(inc, d, 64);
            if (lane >= d) inc += tpl;
        }
        if (lane == 63) wsum[wv] = inc;
        __syncthreads();
        int wexcl = 0;
        for (int k = 0; k < 16; k++) wexcl += (k < wv) ? wsum[k] : 0;
        int run = carryS + wexcl + inc - tot;
        __syncthreads();
        for (int q = 0; q < 4; q++) {
            int i = i0 + q;
            if (i < NN) { off[i] = run; cursor[i] = run; }
            run += v[q];
        }
        if (tid == 1023) carryS = run;
        __syncthreads();
    }
    if (threadIdx.x == 0) off[NN] = carryS;
}

__global__ __launch_bounds__(256) void k_dinv(float* deg_dinv, float* snorm) {
    int n = blockIdx.x * 256 + threadIdx.x;
    if (n < NN) {
        float d = rsqrtf(deg_dinv[n]);
        deg_dinv[n] = d;
        snorm[n] = d * d;   // self-loop norm contribution
    }
}

// Fill CSR buckets: rowv/nrmv per destination; accumulate snorm.
__global__ __launch_bounds__(256) void k_fill(const int* __restrict__ ei,
                                              const float* __restrict__ dinv,
                                              int* __restrict__ cursor,
                                              int* __restrict__ rowv,
                                              float* __restrict__ nrmv,
                                              float* __restrict__ snorm) {
    int e = blockIdx.x * 256 + threadIdx.x;
    if (e >= EE) return;
    int r = ei[e], c = ei[EE + e];
    float nrm = dinv[r] * dinv[c];
    int p = atomicAdd(&cursor[c], 1);
    rowv[p] = r;
    nrmv[p] = nrm;
    atomicAdd(&snorm[c], nrm);
}

// Wc = W_ih @ gcn_W (192x16 row-major), wb = W_ih @ gcn_b
__global__ __launch_bounds__(256) void k_prep(const float* __restrict__ Wih,
                                              const float* __restrict__ gcnW,
                                              const float* __restrict__ gcnb,
                                              float* wc, float* wb) {
    int tid = blockIdx.x * 256 + threadIdx.x;
    if (tid < 3072) {
        int f = tid & 15, row = tid >> 4;
        float s = 0.f;
        for (int k = 0; k < 64; k++) s += Wih[row * 64 + k] * gcnW[k * 16 + f];
        wc[row * 16 + f] = s;
    } else if (tid < 3264) {
        int row = tid - 3072;
        float s = 0.f;
        for (int k = 0; k < 64; k++) s += Wih[row * 64 + k] * gcnb[k];
        wb[row] = s;
    }
}

// Pack GRU weights for MFMA: 256 rows x 96 k (bf16 hi/lo) + bias tables.
// rows 0..127: [Whh | Wc | 0]  (r,z combined)
// rows 128..191: [Whh_n | 0 | 0]   (gh_n)
// rows 192..255: [0 | Wc_n | 0]    (gi_n)
__global__ __launch_bounds__(256) void k_prep2(const float* __restrict__ whh,
                                               const float* __restrict__ wc,
                                               const float* __restrict__ wb,
                                               const float* __restrict__ bih,
                                               const float* __restrict__ bhh,
                                               ushort* __restrict__ pkh,
                                               ushort* __restrict__ pkl,
                                               float* __restrict__ biasA,
                                               float* __restrict__ biasB) {
    int row = threadIdx.x;
    int g = (row < 192) ? row : row - 64;
    for (int k = 0; k < 96; k++) {
        float v = 0.f;
        if (row < 128)      v = (k < 64) ? whh[row * 64 + k] : ((k < 80) ? wc[row * 16 + k - 64] : 0.f);
        else if (row < 192) v = (k < 64) ? whh[row * 64 + k] : 0.f;
        else                v = (k >= 64 && k < 80) ? wc[g * 16 + k - 64] : 0.f;
        ushort hb = f2bf(v);
        pkh[row * 96 + k] = hb;
        pkl[row * 96 + k] = f2bf(v - bf2f(hb));
    }
    float ba, bb;
    if (row < 128)      { ba = bih[row] + bhh[row]; bb = wb[row]; }
    else if (row < 192) { ba = bhh[row];            bb = 0.f; }
    else                { ba = bih[g];              bb = wb[g]; }
    biasA[row] = ba;
    biasB[row] = bb;
}

// Padded bf16 hi/lo copy of e1W ([128][160], k>=132 zero) + (e1b,e2W) float2 table.
__global__ __launch_bounds__(256) void k_prepw(const float* __restrict__ e1W,
                                               const float* __restrict__ e1b,
                                               const float* __restrict__ e2W,
                                               ushort* __restrict__ wph,
                                               ushort* __restrict__ wpl,
                                               float2* __restrict__ b1w2) {
    int idx = blockIdx.x * 256 + threadIdx.x;
    if (idx < 20480) {
        int h = idx / 160, k = idx - h * 160;
        float v = (k < 132) ? e1W[h * 132 + k] : 0.f;
        ushort hb = f2bf(v);
        wph[idx] = hb;
        wpl[idx] = f2bf(v - bf2f(hb));
    } else if (idx < 20608) {
        int h = idx - 20480;
        b1w2[h] = make_float2(e1b[h], e2W[h]);
    }
}

// Gather: one wave per node; lane = (t = lane>>2, f4 = lane&3).
// Emits agg directly as bf16 hi/lo [n][t][16].
__global__ __launch_bounds__(256) void k_gather(const float* __restrict__ x,
                                                const float* __restrict__ dinv,
                                                const int* __restrict__ off,
                                                const int* __restrict__ rowv,
                                                const float* __restrict__ nrmv,
                                                ushort* __restrict__ aggh,
                                                ushort* __restrict__ aggl) {
    int wv = threadIdx.x >> 6, lane = threadIdx.x & 63;
    int n = blockIdx.x * 4 + wv;
    if (n >= NN) return;
    int t = lane >> 2, f4 = lane & 3;
    int s = off[n], e = off[n + 1];
    size_t toff = ((size_t)t * NN) * 16 + f4 * 4;
    float4 acc = make_float4(0.f, 0.f, 0.f, 0.f);
    int i = s;
    for (; i + 1 < e; i += 2) {
        int r0 = rowv[i],     r1 = rowv[i + 1];
        float m0 = nrmv[i],   m1 = nrmv[i + 1];
        float4 v0 = *(const float4*)(x + toff + (size_t)r0 * 16);
        float4 v1 = *(const float4*)(x + toff + (size_t)r1 * 16);
        acc.x += m0 * v0.x; acc.y += m0 * v0.y; acc.z += m0 * v0.z; acc.w += m0 * v0.w;
        acc.x += m1 * v1.x; acc.y += m1 * v1.y; acc.z += m1 * v1.z; acc.w += m1 * v1.w;
    }
    if (i < e) {
        int r0 = rowv[i];
        float m0 = nrmv[i];
        float4 v0 = *(const float4*)(x + toff + (size_t)r0 * 16);
        acc.x += m0 * v0.x; acc.y += m0 * v0.y; acc.z += m0 * v0.z; acc.w += m0 * v0.w;
    }
    float d = dinv[n], d2 = d * d;
    float4 vs = *(const float4*)(x + toff + (size_t)n * 16);
    acc.x += d2 * vs.x; acc.y += d2 * vs.y; acc.z += d2 * vs.z; acc.w += d2 * vs.w;

    ushort4 hv, lv;
    hv.x = f2bf(acc.x); lv.x = f2bf(acc.x - bf2f(hv.x));
    hv.y = f2bf(acc.y); lv.y = f2bf(acc.y - bf2f(hv.y));
    hv.z = f2bf(acc.z); lv.z = f2bf(acc.z - bf2f(hv.z));
    hv.w = f2bf(acc.w); lv.w = f2bf(acc.w - bf2f(hv.w));
    size_t ao = (size_t)n * 256 + t * 16 + f4 * 4;
    *(ushort4*)(aggh + ao) = hv;
    *(ushort4*)(aggl + ao) = lv;
}

// MFMA GRU: block = 64 nodes, 4 waves. Wave w owns gate-blocks {w,4+w,8+w,12+w}
// -> each lane holds r,z,gh_n,gi_n for the same (node, j=16w+lr): in-register update.
// h round-trips through double-buffered LDS bf16 hi/lo tiles (stride 68: 2-way free).
__global__ __launch_bounds__(256, 2) void k_gru2(const ushort* __restrict__ aggh,
                                                 const ushort* __restrict__ aggl,
                                                 const float* __restrict__ snorm,
                                                 const ushort* __restrict__ pkh,
                                                 const ushort* __restrict__ pkl,
                                                 const float* __restrict__ biasA,
                                                 const float* __restrict__ biasB,
                                                 float* __restrict__ emb) {
    __shared__ ushort hHi[2][64][68];
    __shared__ ushort hLo[2][64][68];
    int tid = threadIdx.x;
    int w = tid >> 6, l = tid & 63;
    int lg = l >> 4, lr = l & 15;
    int base = blockIdx.x * 64;
    int j = w * 16 + lr;

    for (int i = tid; i < 64 * 68; i += 256) {
        ((ushort*)hHi)[i] = 0;   // zero buffer 0 only
        ((ushort*)hLo)[i] = 0;
    }

    // B fragments (held in registers for the whole kernel)
    short8 Bh[4][3], Bl[4][3];
    #pragma unroll
    for (int i = 0; i < 4; i++) {
        int row = i * 64 + j;
        #pragma unroll
        for (int ks = 0; ks < 3; ks++) {
            if ((i < 2) || (i == 2 && ks < 2) || (i == 3 && ks == 2)) {
                Bh[i][ks] = *(const short8*)(pkh + row * 96 + ks * 32 + lg * 8);
                Bl[i][ks] = *(const short8*)(pkl + row * 96 + ks * 32 + lg * 8);
            }
        }
    }
    float bA[4], bB[4];
    #pragma unroll
    for (int i = 0; i < 4; i++) {
        bA[i] = biasA[i * 64 + j];
        bB[i] = biasB[i * 64 + j];
    }
    float snr[4][4], hold[4][4];
    #pragma unroll
    for (int tl = 0; tl < 4; tl++)
        #pragma unroll
        for (int q = 0; q < 4; q++) {
            int n = base + tl * 16 + lg * 4 + q;
            snr[tl][q] = snorm[min(n, NN - 1)];
            hold[tl][q] = 0.f;
        }
    int nA[4];
    #pragma unroll
    for (int tl = 0; tl < 4; tl++) nA[tl] = min(base + tl * 16 + lr, NN - 1);

    __syncthreads();

    #pragma unroll 1
    for (int t = 0; t < TT; t++) {
        int cur = t & 1, nxt = cur ^ 1;
        f32x4 acc[4][4];
        #pragma unroll
        for (int i = 0; i < 4; i++)
            #pragma unroll
            for (int tl = 0; tl < 4; tl++)
                #pragma unroll
                for (int q = 0; q < 4; q++)
                    acc[i][tl][q] = bA[i] + snr[tl][q] * bB[i];

        #pragma unroll
        for (int tl = 0; tl < 4; tl++) {
            int nd = tl * 16 + lr;
            const ushort* ph = &hHi[cur][nd][lg * 8];
            const ushort* pl = &hLo[cur][nd][lg * 8];
            short8 Ah0 = ld8u(ph);
            short8 Ah1 = ld8u(ph + 32);
            short8 Al0 = ld8u(pl);
            short8 Al1 = ld8u(pl + 32);
            short8 Ah2 = {0,0,0,0,0,0,0,0};
            short8 Al2 = {0,0,0,0,0,0,0,0};
            if (lg < 2) {
                size_t ao = (size_t)nA[tl] * 256 + t * 16 + lg * 8;
                Ah2 = *(const short8*)(aggh + ao);
                Al2 = *(const short8*)(aggl + ao);
            }
            acc[0][tl] = mfma3(Ah0, Al0, Bh[0][0], Bl[0][0], acc[0][tl]);
            acc[0][tl] = mfma3(Ah1, Al1, Bh[0][1], Bl[0][1], acc[0][tl]);
            acc[0][tl] = mfma3(Ah2, Al2, Bh[0][2], Bl[0][2], acc[0][tl]);
            acc[1][tl] = mfma3(Ah0, Al0, Bh[1][0], Bl[1][0], acc[1][tl]);
            acc[1][tl] = mfma3(Ah1, Al1, Bh[1][1], Bl[1][1], acc[1][tl]);
            acc[1][tl] = mfma3(Ah2, Al2, Bh[1][2], Bl[1][2], acc[1][tl]);
            acc[2][tl] = mfma3(Ah0, Al0, Bh[2][0], Bl[2][0], acc[2][tl]);
            acc[2][tl] = mfma3(Ah1, Al1, Bh[2][1], Bl[2][1], acc[2][tl]);
            acc[3][tl] = mfma3(Ah2, Al2, Bh[3][2], Bl[3][2], acc[3][tl]);
        }

        // In-register GRU update; write h_{t+1} to the other LDS buffer.
        #pragma unroll
        for (int tl = 0; tl < 4; tl++)
            #pragma unroll
            for (int q = 0; q < 4; q++) {
                float r = 1.f / (1.f + __expf(-acc[0][tl][q]));
                float z = 1.f / (1.f + __expf(-acc[1][tl][q]));
                float a = acc[3][tl][q] + r * acc[2][tl][q];
                a = fminf(fmaxf(a, -15.f), 15.f);
                float e2 = __expf(2.f * a);
                float nnv = (e2 - 1.f) / (e2 + 1.f);
                float hv = (1.f - z) * nnv + z * hold[tl][q];
                hold[tl][q] = hv;
                ushort hb = f2bf(hv);
                int nd = tl * 16 + lg * 4 + q;
                hHi[nxt][nd][j] = hb;
                hLo[nxt][nd][j] = f2bf(hv - bf2f(hb));
            }
        __syncthreads();
    }

    #pragma unroll
    for (int tl = 0; tl < 4; tl++)
        #pragma unroll
        for (int q = 0; q < 4; q++) {
            int n = base + tl * 16 + lg * 4 + q;
            if (n < NN) emb[(size_t)n * 64 + j] = hold[tl][q];
        }
}

// Convert emb (N*64 = 3.2M) and ea (E*4 = 3.2M) to bf16 hi/lo.
__global__ __launch_bounds__(256) void k_cvt(const float* __restrict__ emb,
                                             const float* __restrict__ ea,
                                             ushort* __restrict__ embh,
                                             ushort* __restrict__ embl,
                                             ushort* __restrict__ eah,
                                             ushort* __restrict__ eal) {
    int i = blockIdx.x * 256 + threadIdx.x;
    if (i >= 3200000) return;
    float v = emb[i];
    ushort hb = f2bf(v);
    embh[i] = hb;
    embl[i] = f2bf(v - bf2f(hb));
    float u = ea[i];
    ushort hb2 = f2bf(u);
    eah[i] = hb2;
    eal[i] = f2bf(u - bf2f(hb2));
}

// Edge MLP via MFMA, bf16 hi/lo split (3 passes = f32-accurate).
__global__ __launch_bounds__(256) void k_edge(const ushort* __restrict__ embh,
                                              const ushort* __restrict__ embl,
                                              const ushort* __restrict__ eah,
                                              const ushort* __restrict__ eal,
                                              const ushort* __restrict__ wph,
                                              const ushort* __restrict__ wpl,
                                              const float2* __restrict__ b1w2,
                                              const int* __restrict__ ei,
                                              const float* __restrict__ e2b,
                                              float* __restrict__ pred_edge,
                                              float* __restrict__ flow) {
    int w = threadIdx.x >> 6, l = threadIdx.x & 63;
    int lg = l >> 4, lr = l & 15;
    int ebase = (blockIdx.x * 4 + w) * 32;

    short8 Ah[2][5], Al[2][5];
    for (int s = 0; s < 2; s++) {
        int e = ebase + s * 16 + lr;
        int r = ei[e], c = ei[EE + e];
        for (int ks = 0; ks < 4; ks++) {
            int src = (ks < 2) ? r : c;
            int kk = (ks & 1) * 32 + lg * 8;
            Ah[s][ks] = *(const short8*)(embh + (size_t)src * 64 + kk);
            Al[s][ks] = *(const short8*)(embl + (size_t)src * 64 + kk);
        }
        short8 zh = {0, 0, 0, 0, 0, 0, 0, 0};
        short8 zl = {0, 0, 0, 0, 0, 0, 0, 0};
        if (lg == 0) {
            const uint* ph4 = (const uint*)(eah + (size_t)e * 4);
            const uint* pl4 = (const uint*)(eal + (size_t)e * 4);
            ((uint*)&zh)[0] = ph4[0]; ((uint*)&zh)[1] = ph4[1];
            ((uint*)&zl)[0] = pl4[0]; ((uint*)&zl)[1] = pl4[1];
        }
        Ah[s][4] = zh;
        Al[s][4] = zl;
    }

    float esum[2][4];
    for (int s = 0; s < 2; s++)
        for (int q = 0; q < 4; q++) esum[s][q] = 0.f;

    for (int nt = 0; nt < 8; nt++) {
        int n0 = nt * 16;
        f32x4 acc[2] = {{0.f, 0.f, 0.f, 0.f}, {0.f, 0.f, 0.f, 0.f}};
        const ushort* wbh = wph + (size_t)(n0 + lr) * 160 + lg * 8;
        const ushort* wbl = wpl + (size_t)(n0 + lr) * 160 + lg * 8;
        for (int ks = 0; ks < 5; ks++) {
            short8 bh = *(const short8*)(wbh + ks * 32);
            short8 bl = *(const short8*)(wbl + ks * 32);
            for (int s = 0; s < 2; s++) {
                acc[s] = __builtin_amdgcn_mfma_f32_16x16x32_bf16(Ah[s][ks], bh, acc[s], 0, 0, 0);
                acc[s] = __builtin_amdgcn_mfma_f32_16x16x32_bf16(Ah[s][ks], bl, acc[s], 0, 0, 0);
                acc[s] = __builtin_amdgcn_mfma_f32_16x16x32_bf16(Al[s][ks], bh, acc[s], 0, 0, 0);
            }
        }
        float2 bw = b1w2[n0 + lr];
        for (int s = 0; s < 2; s++)
            for (int q = 0; q < 4; q++)
                esum[s][q] += fmaxf(acc[s][q] + bw.x, 0.f) * bw.y;
    }
    for (int m = 1; m < 16; m <<= 1)
        for (int s = 0; s < 2; s++)
            for (int q = 0; q < 4; q++)
                esum[s][q] += __shfl_xor(esum[s][q], m, 64);
    if (lr == 0) {
        float eb = e2b[0];
        for (int s = 0; s < 2; s++)
            for (int q = 0; q < 4; q++) {
                int e = ebase + s * 16 + lg * 4 + q;
                float pv = esum[s][q] + eb;
                pred_edge[e] = pv;
                atomicAdd(&flow[ei[EE + e]], pv);
            }
    }
}

// Node MLP: one wave per node, lane j = hidden unit j
__global__ __launch_bounds__(256) void k_node(const float* __restrict__ emb,
                                              const float* __restrict__ flow,
                                              const float* __restrict__ p1W,
                                              const float* __restrict__ p1b,
                                              const float* __restrict__ p2W,
                                              const float* __restrict__ p2b,
                                              float* __restrict__ out) {
    int w = threadIdx.x >> 6, j = threadIdx.x & 63;
    int n = blockIdx.x * 4 + w;
    if (n >= NN) return;
    const float* wrow = p1W + j * 65;
    const float* ev = emb + (size_t)n * 64;
    float acc = p1b[j];
    for (int f = 0; f < 64; f++) acc += wrow[f] * ev[f];
    acc += wrow[64] * flow[n];
    float val = p2W[j] * fmaxf(acc, 0.f);
    for (int m = 1; m < 64; m <<= 1) val += __shfl_xor(val, m, 64);
    if (j == 0) out[n] = val + p2b[0];
}

extern "C" void kernel_launch(void* const* d_in, const int* in_sizes, int n_in,
                              void* d_out, int out_size, void* d_ws, size_t ws_size,
                              hipStream_t stream) {
    (void)in_sizes; (void)n_in; (void)out_size; (void)ws_size;
    const float* x    = (const float*)d_in[0];
    const float* ea   = (const float*)d_in[1];
    const float* gcnW = (const float*)d_in[2];
    const float* gcnb = (const float*)d_in[3];
    const float* Wih  = (const float*)d_in[4];
    const float* Whh  = (const float*)d_in[5];
    const float* bih  = (const float*)d_in[6];
    const float* bhh  = (const float*)d_in[7];
    const float* e1W  = (const float*)d_in[8];
    const float* e1b  = (const float*)d_in[9];
    const float* e2W  = (const float*)d_in[10];
    const float* e2b  = (const float*)d_in[11];
    const float* p1W  = (const float*)d_in[12];
    const float* p1b  = (const float*)d_in[13];
    const float* p2W  = (const float*)d_in[14];
    const float* p2b  = (const float*)d_in[15];
    const int*   ei   = (const int*)d_in[16];

    char* ws = (char*)d_ws;
    float*  dinv  = (float*)(ws + WS_DINV);
    float*  snorm = (float*)(ws + WS_SNORM);
    float*  flow  = (float*)(ws + WS_FLOW);
    float*  wc    = (float*)(ws + WS_WC);
    float*  wb    = (float*)(ws + WS_WB);
    float*  emb   = (float*)(ws + WS_EMB);
    ushort* aggh  = (ushort*)(ws + WS_AGGH);
    ushort* aggl  = (ushort*)(ws + WS_AGGL);
    ushort* embh  = (ushort*)(ws + WS_EMBH);
    ushort* embl  = (ushort*)(ws + WS_EMBL);
    ushort* eah   = (ushort*)(ws + WS_EAH);
    ushort* eal   = (ushort*)(ws + WS_EAL);
    int*    off   = (int*)(ws + WS_OFF);
    int*    cur   = (int*)(ws + WS_CUR);
    int*    rowv  = (int*)(ws + WS_ROWV);
    float*  nrmv  = (float*)(ws + WS_NRMV);
    ushort* pkh   = (ushort*)(ws + WS_PKH);
    ushort* pkl   = (ushort*)(ws + WS_PKL);
    float*  biasA = (float*)(ws + WS_BA);
    float*  biasB = (float*)(ws + WS_BB);
    ushort* wph   = (ushort*)(ws + WS_WPH);
    ushort* wpl   = (ushort*)(ws + WS_WPL);
    float2* b1w2  = (float2*)(ws + WS_B1W2);

    float* pred_node = (float*)d_out;
    float* pred_edge = (float*)d_out + NN;

    k_init<<<(NN + 255) / 256, 256, 0, stream>>>(dinv, flow);
    k_deg<<<(EE + 255) / 256, 256, 0, stream>>>(ei, dinv);
    k_scan<<<1, 1024, 0, stream>>>(dinv, off, cur);
    k_dinv<<<(NN + 255) / 256, 256, 0, stream>>>(dinv, snorm);
    k_prep<<<13, 256, 0, stream>>>(Wih, gcnW, gcnb, wc, wb);
    k_prepw<<<81, 256, 0, stream>>>(e1W, e1b, e2W, wph, wpl, b1w2);
    k_fill<<<(EE + 255) / 256, 256, 0, stream>>>(ei, dinv, cur, rowv, nrmv, snorm);
    k_gather<<<(NN + 3) / 4, 256, 0, stream>>>(x, dinv, off, rowv, nrmv, aggh, aggl);
    k_prep2<<<1, 256, 0, stream>>>(Whh, wc, wb, bih, bhh, pkh, pkl, biasA, biasB);  // after k_gather: overlays nrmv
    k_gru2<<<(NN + 63) / 64, 256, 0, stream>>>(aggh, aggl, snorm, pkh, pkl, biasA, biasB, emb);
    k_cvt<<<(3200000 + 255) / 256, 256, 0, stream>>>(emb, ea, embh, embl, eah, eal);
    k_edge<<<EE / 128, 256, 0, stream>>>(embh, embl, eah, eal, wph, wpl, b1w2, ei, e2b, pred_edge, flow);
    k_node<<<(NN + 3) / 4, 256, 0, stream>>>(emb, flow, p1W, p1b, p2W, p2b, pred_node);
}